// Round 4
// baseline (283.345 us; speedup 1.0000x reference)
//
#include <hip/hip_runtime.h>
#include <math.h>

#define D_MODEL 128
#define N_STATE 64
#define SEQ_L   4096
#define CHUNK   2
#define GRID    (SEQ_L / CHUNK)   // 2048 blocks; 4-5 resident per CU

typedef __attribute__((ext_vector_type(8))) __bf16 bf16x8;
typedef __attribute__((ext_vector_type(4))) float  f32x4;

// K[i] = (C . a^i) @ B, A diagonal. Computed TRANSPOSED via MFMA operand swap:
//   D_tile = (B^T-frag as A-op) x (Cs^T-frag as B-op)  ==> D[m][n] = K[n'][m']
// mfma_f32_16x16x32_bf16 layouts (verified): A-op A[m=lane&15][k=8q+j],
// B-op B[k=8q+j][n=lane&15], C/D row m=4q+reg, col n=lane&15.
//
// R0-R3 lesson: store schedule (scattered vs LDS-coalesced vs raw-barrier)
// is IRRELEVANT — all land at ~105us vs 41us write roofline. Invariant was
// 2 waves/SIMD. R4 theory: store-data VGPR recycling each step forces
// expcnt/vmcnt WAR waits gated by the clogged write pipe; 2 waves/SIMD can't
// cover them. Fix: cut VGPR ~200 -> ~110 (B to LDS, kill Bfrag[64] and
// acc[64] via immediate per-tile stores) -> 4 waves/SIMD, 4-5 blocks/CU,
// zero main-loop barriers.
__global__ __launch_bounds__(256, 4) void s4d_mfma_kernel(
    const float* __restrict__ A,   // 64x64 diagonal
    const float* __restrict__ B,   // 64x128
    const float* __restrict__ C,   // 128x64
    float* __restrict__ K)         // L x 128 x 128
{
    // B^T in LDS as bf16, XOR-swizzled. 16B slot (col, rb) holds rows
    // [8rb, 8rb+8) of column col; phys16 = col*8 + (rb ^ (col&7)).
    // Fragment read (c,s) lane(q,ln): rb = 4s+q, col = 16c+ln ->
    // bank = 4*((4s+q)^(ln&7)) -> 8 distinct 16B slots, 8 lanes each
    // = optimal 8-phase, conflict-free ds_read_b128.
    __shared__ __align__(16) __bf16 Blds[N_STATE * D_MODEL];  // 16 KiB

    const int tid  = threadIdx.x;
    const int w    = tid >> 6;     // wave 0..3: owns K-rows [32w, 32w+32)
    const int lane = tid & 63;
    const int ln   = lane & 15;
    const int q    = lane >> 4;
    const int i0   = blockIdx.x * CHUNK;

    // one-time stage of B^T into LDS (col contiguous per tid -> coalesced)
    for (int e = tid; e < N_STATE * D_MODEL; e += 256) {
        const int row = e >> 7;       // 0..63
        const int col = e & 127;      // 0..127
        const int rb  = row >> 3;
        const int p16 = col * 8 + (rb ^ (col & 7));
        Blds[p16 * 8 + (row & 7)] = (__bf16)B[row * D_MODEL + col];
    }

    // avec[s][j] = a_k, Csval[t][s][j] = C[d][k] * a_k^i0   (k = 32s+8q+j,
    // d = 32w+16t+ln).  Scaled C carried forward: Csval *= avec per step.
    float avec[2][8], Csval[2][2][8];
    #pragma unroll
    for (int s = 0; s < 2; ++s)
        #pragma unroll
        for (int j = 0; j < 8; ++j) {
            const int k = 32*s + 8*q + j;
            const float a = A[k * N_STATE + k];
            avec[s][j] = a;
            const float p = powf(a, (float)i0);   // powf(0,0)=1 handles i0=0
            #pragma unroll
            for (int t = 0; t < 2; ++t)
                Csval[t][s][j] = C[(32*w + 16*t + ln) * N_STATE + k] * p;
        }

    __syncthreads();   // Blds ready (prologue only; main loop barrier-free)

    // per-lane LDS byte addresses for the two k-halves (c folds into the
    // ds_read immediate offset: +2048 bytes per c)
    const int addr_s0 = (8*ln + ( q      ^ (ln & 7))) * 16;
    const int addr_s1 = (8*ln + ((4 + q) ^ (ln & 7))) * 16;
    const char* ldsb = (const char*)Blds;

    float* out = K + (size_t)i0 * (D_MODEL * D_MODEL);

    for (int i = 0; i < CHUNK; ++i) {
        #pragma unroll
        for (int t = 0; t < 2; ++t) {
            // current scaled C -> bf16 B-operand frags (8 VGPRs live)
            bf16x8 cf0, cf1;
            #pragma unroll
            for (int j = 0; j < 8; ++j) {
                cf0[j] = (__bf16)Csval[t][0][j];
                cf1[j] = (__bf16)Csval[t][1][j];
            }
            float* rowp = out + (32*w + 16*t + ln) * D_MODEL + 4*q;
            #pragma unroll
            for (int c = 0; c < 8; ++c) {
                const bf16x8 b0 =
                    *reinterpret_cast<const bf16x8*>(ldsb + addr_s0 + 2048*c);
                const bf16x8 b1 =
                    *reinterpret_cast<const bf16x8*>(ldsb + addr_s1 + 2048*c);
                f32x4 z = {0.f, 0.f, 0.f, 0.f};
                f32x4 d = __builtin_amdgcn_mfma_f32_16x16x32_bf16(
                    b0, cf0, z, 0, 0, 0);
                d = __builtin_amdgcn_mfma_f32_16x16x32_bf16(
                    b1, cf1, d, 0, 0, 0);
                // immediate per-tile store: K[32w+16t+ln][16c+4q .. +3]
                *(float4*)(rowp + 16*c) = make_float4(d[0], d[1], d[2], d[3]);
            }
        }

        // advance scaled C by one power of the diagonal
        #pragma unroll
        for (int t = 0; t < 2; ++t)
            #pragma unroll
            for (int s = 0; s < 2; ++s)
                #pragma unroll
                for (int j = 0; j < 8; ++j)
                    Csval[t][s][j] *= avec[s][j];

        out += D_MODEL * D_MODEL;
    }
}

extern "C" void kernel_launch(void* const* d_in, const int* in_sizes, int n_in,
                              void* d_out, int out_size, void* d_ws, size_t ws_size,
                              hipStream_t stream) {
    const float* A = (const float*)d_in[0];
    const float* B = (const float*)d_in[1];
    const float* C = (const float*)d_in[2];
    float* K = (float*)d_out;
    s4d_mfma_kernel<<<dim3(GRID), dim3(256), 0, stream>>>(A, B, C, K);
}